// Round 6
// baseline (537.369 us; speedup 1.0000x reference)
//
#include <hip/hip_runtime.h>
#include <stdint.h>

#define C 128

typedef __attribute__((ext_vector_type(8))) short bfrag;   // 8 x bf16 (4 VGPRs)
typedef __attribute__((ext_vector_type(4))) float ffrag;   // 4 x f32 accum

__device__ __forceinline__ unsigned short f2bf(float f){
  union { float f; unsigned int i; } v; v.f = f;
  unsigned int x = v.i;
  unsigned int r = x + 0x7fffu + ((x >> 16) & 1u);   // round-to-nearest-even
  return (unsigned short)(r >> 16);
}
__device__ __forceinline__ float bf2f(unsigned short u){
  union { unsigned int i; float f; } v; v.i = ((unsigned int)u) << 16; return v.f;
}

// ---------------- zero deg64 ----------------
__global__ void k_zero_region(unsigned int* base, int nwords){
  int i = blockIdx.x * 256 + threadIdx.x;
  if (i < nwords) base[i] = 0u;
}

// ---------------- prep1: {deg/cnt atomics | x->cur0/curT | weight casts} ----------------
// deg64: high 32 = count, low 32 = weight in 24-bit fixed point; atomic return = rank.
__global__ __launch_bounds__(256) void k_prep1(
    const int* __restrict__ row, const float* __restrict__ w,
    unsigned long long* deg64, int* __restrict__ rank, int E, int degB,
    const float* __restrict__ x, unsigned short* __restrict__ cur0,
    unsigned short* __restrict__ curT, int N, int prepB,
    const float* __restrict__ Wq, const float* __restrict__ Wk,
    const float* __restrict__ Wo, unsigned short* __restrict__ W16, int WW){
  __shared__ unsigned short tile[64][66];
  int bx = blockIdx.x;
  if (bx < degB){
    int e = bx * 256 + threadIdx.x;
    if (e < E){
      int r = row[e];
      unsigned int wf = (unsigned int)(w[e] * 16777216.0f + 0.5f);   // w * 2^24
      unsigned long long old =
          atomicAdd(&deg64[r], 0x100000000ULL | (unsigned long long)wf);
      rank[e] = (int)(old >> 32);
    }
    return;
  }
  bx -= degB;
  if (bx < prepB){
    int ntiles = N >> 6;
    int n0 = (bx % ntiles) * 64;
    int c0 = (bx / ntiles) * 64;
    int tx = threadIdx.x & 63, ty = threadIdx.x >> 6;
    for (int r = ty; r < 64; r += 4){
      float v = x[(size_t)(n0 + r) * C + c0 + tx];
      unsigned short u = f2bf(v);
      cur0[(size_t)(n0 + r) * C + c0 + tx] = u;
      tile[r][tx] = u;
    }
    __syncthreads();
    for (int r = ty; r < 64; r += 4)
      curT[(size_t)(c0 + r) * N + n0 + tx] = tile[tx][r];
    return;
  }
  bx -= prepB;
  int i = bx * 256 + threadIdx.x;
  if (i < 3 * WW){
    const float* src = (i < WW) ? Wq : ((i < 2 * WW) ? Wk : Wo);
    int off = (i < WW) ? 0 : ((i < 2 * WW) ? WW : 2 * WW);
    W16[i] = f2bf(src[i - off]);
  }
}

// ---- scan stage 1: per-block sums of cnt (decoded from deg64) + dinv decode ----
__global__ void k_scan1(const unsigned long long* __restrict__ deg64,
                        float* __restrict__ dinv, int* bsum, int N){
  __shared__ int s[256];
  int b = blockIdx.x, t = threadIdx.x;
  int i = b * 256 + t;
  int cnt = 0;
  if (i < N){
    unsigned long long v = deg64[i];
    cnt = (int)(v >> 32);
    unsigned int lo = (unsigned int)v;
    float d = (float)lo * (1.0f / 16777216.0f);
    dinv[i] = lo > 0u ? 1.0f / sqrtf(d) : 0.f;
  }
  s[t] = cnt;
  __syncthreads();
  for (int o = 128; o; o >>= 1){ if (t < o) s[t] += s[t + o]; __syncthreads(); }
  if (t == 0) bsum[b] = s[0];
}

// ---- scan stage 2: each block sums bsum[0..b) itself, then local inclusive scan ----
__global__ void k_scan3(const unsigned long long* __restrict__ deg64,
                        const int* __restrict__ bsum, int* row_ptr, int N){
  __shared__ int s[256];
  int b = blockIdx.x, t = threadIdx.x;
  int i = b * 256 + t;
  int v = (i < N) ? (int)(deg64[i] >> 32) : 0;
  s[t] = v;
  __syncthreads();
  for (int o = 1; o < 256; o <<= 1){
    int u = (t >= o) ? s[t - o] : 0;
    __syncthreads(); s[t] += u; __syncthreads();
  }
  int base = 0;
  for (int j = 0; j < b; j++) base += bsum[j];
  int excl = base + s[t] - v;
  if (i < N) row_ptr[i] = excl;
  if (i == N - 1) row_ptr[N] = excl + v;
}

// ---------------- prep2: {CSR fill | both projections [MFMA]} ----------------
__global__ __launch_bounds__(256) void k_prep2(
    const int* __restrict__ row, const int* __restrict__ col,
    const float* __restrict__ w, const int* __restrict__ rank,
    const int* __restrict__ row_ptr, const float* __restrict__ dinv,
    int2* __restrict__ edge_s, int E, int fillB,
    const unsigned short* __restrict__ x, const unsigned short* __restrict__ W16,
    const float* __restrict__ Wq_b, const float* __restrict__ Wk_b,
    unsigned short* __restrict__ qs, unsigned short* __restrict__ ksT,
    int N, int wblocks){
  int bx = blockIdx.x;
  if (bx < fillB){
    int e = bx * 256 + threadIdx.x;
    if (e < E){
      int r = row[e], c = col[e];
      int p = row_ptr[r] + rank[e];
      float cf = dinv[r] * dinv[c] * w[e];
      int2 ed; ed.x = c; ed.y = __float_as_int(cf);
      edge_s[p] = ed;
    }
    return;
  }
  bx -= fillB;
  int transposed = bx >= wblocks;
  int lb = transposed ? bx - wblocks : bx;
  const unsigned short* W = transposed ? (W16 + C * C) : W16;
  const float* Wb = transposed ? Wk_b : Wq_b;
  unsigned short* out = transposed ? ksT : qs;

  int wv = threadIdx.x >> 6, l = threadIdx.x & 63;
  int m0 = (lb * 4 + wv) * 16;
  if (m0 >= N) return;
  int quad = l >> 4, lcol = l & 15;
  ffrag acc[8] = {};
  const unsigned short* Abase = x + (size_t)(m0 + lcol) * C + quad * 8;
#pragma unroll
  for (int s = 0; s < 4; s++){
    bfrag a = *(const bfrag*)(Abase + s * 32);
#pragma unroll
    for (int nt = 0; nt < 8; nt++){
      bfrag bb = *(const bfrag*)(W + (size_t)(nt * 16 + lcol) * C + s * 32 + quad * 8);
      acc[nt] = __builtin_amdgcn_mfma_f32_16x16x32_bf16(a, bb, acc[nt], 0, 0, 0);
    }
  }
  float q[8][4];
  float ss[4] = {0.f, 0.f, 0.f, 0.f};
#pragma unroll
  for (int nt = 0; nt < 8; nt++){
    float bias = Wb[nt * 16 + lcol];
#pragma unroll
    for (int r = 0; r < 4; r++){ float v = acc[nt][r] + bias; q[nt][r] = v; ss[r] += v * v; }
  }
#pragma unroll
  for (int off = 1; off < 16; off <<= 1){
#pragma unroll
    for (int r = 0; r < 4; r++) ss[r] += __shfl_xor(ss[r], off, 64);
  }
  float inv[4];
#pragma unroll
  for (int r = 0; r < 4; r++) inv[r] = 1.0f / sqrtf(fmaxf(ss[r], 1e-30f));
  if (!transposed){
#pragma unroll
    for (int nt = 0; nt < 8; nt++)
#pragma unroll
      for (int r = 0; r < 4; r++)
        out[(size_t)(m0 + quad * 4 + r) * C + nt * 16 + lcol] = f2bf(q[nt][r] * inv[r]);
  } else {
#pragma unroll
    for (int nt = 0; nt < 8; nt++){
      ushort4 pk;
      pk.x = f2bf(q[nt][0] * inv[0]); pk.y = f2bf(q[nt][1] * inv[1]);
      pk.z = f2bf(q[nt][2] * inv[2]); pk.w = f2bf(q[nt][3] * inv[3]);
      *(ushort4*)(out + (size_t)(nt * 16 + lcol) * N + m0 + quad * 4) = pk;
    }
  }
}

// ---------------- per-iteration k_M: M-GEMM + vsum (+ksum it0) ----------------
// blocks [0, mB):                 M[b] = Ks_b^T Cur_b  (MFMA)
// blocks [mB, mB+vsB):            vsum[b][d] = sum_n curT[d][b*PG+n]
// blocks [mB+vsB, mB+vsB+ksB):    ksum[b][d] = sum_n ksT[d][b*PG+n]   (it0 only)
__global__ __launch_bounds__(256) void k_M(const unsigned short* __restrict__ ksT,
      const unsigned short* __restrict__ curT, unsigned short* __restrict__ MT,
      float* __restrict__ vsum, float* __restrict__ ksum,
      int N, int PG, int mB, int vsB, int ksB){
  int bx = blockIdx.x;
  if (bx < mB){
    int wv = threadIdx.x >> 6, l = threadIdx.x & 63;
    int b = bx >> 2;
    int gw = (bx & 3) * 4 + wv;
    int itile = gw & 7, jh = gw >> 3;
    int quad = l >> 4, lcol = l & 15;
    ffrag acc[4] = {};
    const unsigned short* Arow = ksT + (size_t)(itile * 16 + lcol) * N + (size_t)b * PG + quad * 8;
    const unsigned short* B0 = curT + (size_t)b * PG + quad * 8;
    int steps = PG / 32;
    for (int s = 0; s < steps; s++){
      bfrag a = *(const bfrag*)(Arow + s * 32);
#pragma unroll
      for (int jt = 0; jt < 4; jt++){
        bfrag bb = *(const bfrag*)(B0 + (size_t)((jh * 4 + jt) * 16 + lcol) * N + s * 32);
        acc[jt] = __builtin_amdgcn_mfma_f32_16x16x32_bf16(a, bb, acc[jt], 0, 0, 0);
      }
    }
    unsigned short* MTb = MT + (size_t)b * C * C;
    int i0 = itile * 16 + quad * 4;
#pragma unroll
    for (int jt = 0; jt < 4; jt++){
      int j = (jh * 4 + jt) * 16 + lcol;
      ushort4 pk;
      pk.x = f2bf(acc[jt][0]); pk.y = f2bf(acc[jt][1]);
      pk.z = f2bf(acc[jt][2]); pk.w = f2bf(acc[jt][3]);
      *(ushort4*)(MTb + (size_t)j * C + i0) = pk;
    }
    return;
  }
  bx -= mB;
  if (bx < vsB + ksB){
    const unsigned short* src = (bx < vsB) ? curT : ksT;
    float* dst = (bx < vsB) ? vsum : ksum;
    int b = (bx < vsB) ? bx : (bx - vsB);
    int wv = threadIdx.x >> 6, l = threadIdx.x & 63;
    for (int d = wv * 32; d < wv * 32 + 32; d++){
      float s = 0.f;
      for (int n0 = l * 8; n0 < PG; n0 += 512){
        bfrag v = *(const bfrag*)(src + (size_t)d * N + (size_t)b * PG + n0);
#pragma unroll
        for (int j = 0; j < 8; j++) s += bf2f((unsigned short)v[j]);
      }
#pragma unroll
      for (int off = 32; off; off >>= 1) s += __shfl_xor(s, off, 64);
      if (l == 0) dst[b * C + d] = s;
    }
  }
}

// ---------------- phase2 [MFMA] with fused GCN gather ----------------
// Per wave: gather gcn rows m0..m0+15 into per-wave LDS (bf16-packed, identical
// rounding to the old gcn32 path), then attn MFMA + combine. No barrier needed:
// each wave reads only its own gbuf rows.
__global__ __launch_bounds__(256) void k_phase2(const unsigned short* __restrict__ qs,
      const unsigned short* __restrict__ MT, const float* __restrict__ vsum,
      const float* __restrict__ ksum, const int* __restrict__ n_nodes,
      float* __restrict__ denom,
      const int* __restrict__ row_ptr, const int2* __restrict__ edge_s,
      const unsigned int* __restrict__ cur32,
      unsigned short* __restrict__ curO, unsigned short* __restrict__ curT,
      int N, int PG, int it0){
  __shared__ unsigned int gbuf[4][16][66];   // stride 66 -> conflict-free epilogue reads
  int wv = threadIdx.x >> 6, l = threadIdx.x & 63;
  int m0 = (blockIdx.x * 4 + wv) * 16;
  if (m0 >= N) return;
  // ---- fused gather: lane = channel-pair, 16 rows sequential ----
  for (int r16 = 0; r16 < 16; r16++){
    int nid = m0 + r16;
    int s = row_ptr[nid], e = row_ptr[nid + 1];
    float a0 = 0.f, a1 = 0.f;
    int p = s;
    for (; p + 4 <= e; p += 4){
      int2 e0 = edge_s[p],     e1 = edge_s[p + 1];
      int2 e2 = edge_s[p + 2], e3 = edge_s[p + 3];
      float f0 = __int_as_float(e0.y), f1 = __int_as_float(e1.y);
      float f2 = __int_as_float(e2.y), f3 = __int_as_float(e3.y);
      unsigned int u0 = cur32[(size_t)e0.x * 64 + l];
      unsigned int u1 = cur32[(size_t)e1.x * 64 + l];
      unsigned int u2 = cur32[(size_t)e2.x * 64 + l];
      unsigned int u3 = cur32[(size_t)e3.x * 64 + l];
      a0 += f0 * bf2f((unsigned short)(u0 & 0xffffu));
      a1 += f0 * bf2f((unsigned short)(u0 >> 16));
      a0 += f1 * bf2f((unsigned short)(u1 & 0xffffu));
      a1 += f1 * bf2f((unsigned short)(u1 >> 16));
      a0 += f2 * bf2f((unsigned short)(u2 & 0xffffu));
      a1 += f2 * bf2f((unsigned short)(u2 >> 16));
      a0 += f3 * bf2f((unsigned short)(u3 & 0xffffu));
      a1 += f3 * bf2f((unsigned short)(u3 >> 16));
    }
    for (; p < e; p++){
      int2 ed = edge_s[p];
      float cf = __int_as_float(ed.y);
      unsigned int u = cur32[(size_t)ed.x * 64 + l];
      a0 += cf * bf2f((unsigned short)(u & 0xffffu));
      a1 += cf * bf2f((unsigned short)(u >> 16));
    }
    gbuf[wv][r16][l] = ((unsigned int)f2bf(a1) << 16) | (unsigned int)f2bf(a0);
  }
  // ---- attn MFMA ----
  int b = m0 / PG;
  int quad = l >> 4, lcol = l & 15;
  ffrag acc[8] = {};
  const unsigned short* Abase = qs + (size_t)(m0 + lcol) * C + quad * 8;
  const unsigned short* MTb = MT + (size_t)b * C * C;
  const float* ksb = ksum + b * C;
  float dsum = 0.f;
#pragma unroll
  for (int s = 0; s < 4; s++){
    bfrag a = *(const bfrag*)(Abase + s * 32);
    if (it0){
#pragma unroll
      for (int j = 0; j < 8; j++)
        dsum += bf2f((unsigned short)a[j]) * ksb[quad * 8 + s * 32 + j];
    }
#pragma unroll
    for (int dt = 0; dt < 8; dt++){
      bfrag bb = *(const bfrag*)(MTb + (size_t)(dt * 16 + lcol) * C + s * 32 + quad * 8);
      acc[dt] = __builtin_amdgcn_mfma_f32_16x16x32_bf16(a, bb, acc[dt], 0, 0, 0);
    }
  }
  float dn[4];
  if (it0){
    dsum += __shfl_xor(dsum, 16, 64);
    dsum += __shfl_xor(dsum, 32, 64);
    float dfull = dsum + (float)n_nodes[b];
    if (quad == 0) denom[m0 + lcol] = dfull;          // persist for later iterations
#pragma unroll
    for (int r = 0; r < 4; r++) dn[r] = __shfl(dfull, quad * 4 + r, 64);
  } else {
#pragma unroll
    for (int r = 0; r < 4; r++) dn[r] = denom[m0 + quad * 4 + r];
  }
#pragma unroll
  for (int dt = 0; dt < 8; dt++){
    int d = dt * 16 + lcol;
    float vs = vsum[b * C + d];
    ushort4 pk;
#pragma unroll
    for (int r = 0; r < 4; r++){
      int m = m0 + quad * 4 + r;
      float attn = (acc[dt][r] + vs) / dn[r];
      unsigned int gw = gbuf[wv][quad * 4 + r][dt * 8 + (lcol >> 1)];
      float g = bf2f((lcol & 1) ? (unsigned short)(gw >> 16)
                                : (unsigned short)(gw & 0xffffu));
      unsigned short nb = f2bf(0.5f * (g + attn));   // BETA = 0.5
      curO[(size_t)m * C + d] = nb;
      ((unsigned short*)&pk)[r] = nb;
    }
    *(ushort4*)(curT + (size_t)d * N + m0 + quad * 4) = pk;
  }
}

// ---------------- out = (x + c1+c2+c3+c4) @ Wo^T + Wo_b  (FP32 OUTPUT)  [MFMA] ----------------
__global__ __launch_bounds__(256) void k_final(const float* __restrict__ x,
      const unsigned short* __restrict__ c1, const unsigned short* __restrict__ c2,
      const unsigned short* __restrict__ c3, const unsigned short* __restrict__ c4,
      const unsigned short* __restrict__ Wo, const float* __restrict__ Wob,
      float* __restrict__ out, int N){
  int wv = threadIdx.x >> 6, l = threadIdx.x & 63;
  int m0 = (blockIdx.x * 4 + wv) * 16;
  if (m0 >= N) return;
  int quad = l >> 4, lcol = l & 15;
  ffrag acc[8] = {};
  size_t rowoff = (size_t)(m0 + lcol) * C + quad * 8;
#pragma unroll
  for (int s = 0; s < 4; s++){
    size_t base = rowoff + s * 32;
    float4 xa0 = *(const float4*)(x + base);
    float4 xa1 = *(const float4*)(x + base + 4);
    bfrag b1 = *(const bfrag*)(c1 + base);
    bfrag b2 = *(const bfrag*)(c2 + base);
    bfrag b3 = *(const bfrag*)(c3 + base);
    bfrag b4 = *(const bfrag*)(c4 + base);
    float xs[8] = {xa0.x, xa0.y, xa0.z, xa0.w, xa1.x, xa1.y, xa1.z, xa1.w};
    bfrag a;
#pragma unroll
    for (int j = 0; j < 8; j++){
      float v = (((xs[j] + bf2f((unsigned short)b1[j])) + bf2f((unsigned short)b2[j]))
                 + bf2f((unsigned short)b3[j])) + bf2f((unsigned short)b4[j]);
      a[j] = (short)f2bf(v);
    }
#pragma unroll
    for (int ot = 0; ot < 8; ot++){
      bfrag bb = *(const bfrag*)(Wo + (size_t)(ot * 16 + lcol) * C + s * 32 + quad * 8);
      acc[ot] = __builtin_amdgcn_mfma_f32_16x16x32_bf16(a, bb, acc[ot], 0, 0, 0);
    }
  }
#pragma unroll
  for (int ot = 0; ot < 8; ot++){
    float bias = Wob[ot * 16 + lcol];
#pragma unroll
    for (int r = 0; r < 4; r++){
      out[(size_t)(m0 + quad * 4 + r) * C + ot * 16 + lcol] = acc[ot][r] + bias;   // fp32 store
    }
  }
}

// ================= host =================

extern "C" void kernel_launch(void* const* d_in, const int* in_sizes, int n_in,
                              void* d_out, int out_size, void* d_ws, size_t ws_size,
                              hipStream_t stream){
  const float* x    = (const float*)d_in[0];
  const int*   eidx = (const int*)d_in[1];
  const float* ew   = (const float*)d_in[2];
  const int*   n_nodes = (const int*)d_in[3];
  const float* Wq_w = (const float*)d_in[4];
  const float* Wq_b = (const float*)d_in[5];
  const float* Wk_w = (const float*)d_in[6];
  const float* Wk_b = (const float*)d_in[7];
  const float* Wo_w = (const float*)d_in[8];
  const float* Wo_b = (const float*)d_in[9];
  float* out = (float*)d_out;                  // fp32 output

  int N = in_sizes[0] / C;
  int E = in_sizes[2];
  int B = in_sizes[3];
  int PG = N / B;
  int BC = B * C;
  const int* row = eidx;
  const int* col = eidx + E;

  char* p = (char*)d_ws;
  auto alloc = [&](size_t bytes) -> void* {
    void* r = (void*)p; p += (bytes + 255) & ~(size_t)255; return r;
  };
  unsigned short* cur[5];
  for (int i = 0; i < 5; i++) cur[i] = (unsigned short*)alloc((size_t)N * C * 2);
  unsigned short* curT  = (unsigned short*)alloc((size_t)N * C * 2);
  unsigned short* qs16  = (unsigned short*)alloc((size_t)N * C * 2);
  unsigned short* ksT   = (unsigned short*)alloc((size_t)N * C * 2);
  unsigned short* MT    = (unsigned short*)alloc((size_t)B * C * C * 2);
  unsigned short* W16   = (unsigned short*)alloc((size_t)3 * C * C * 2);  // Wq|Wk|Wo
  unsigned long long* deg64 = (unsigned long long*)alloc((size_t)N * 8);
  float*          dinv  = (float*)alloc((size_t)N * 4);
  int*            row_ptr = (int*)alloc((size_t)(N + 1) * 4);
  int*            rank  = (int*)alloc((size_t)E * 4);
  int*            bsum  = (int*)alloc(1024);
  int2*           edge_s = (int2*)alloc((size_t)E * 8);
  float*          ksum  = (float*)alloc((size_t)BC * 4);
  float*          vsum  = (float*)alloc((size_t)BC * 4);
  float*          denom = (float*)alloc((size_t)N * 4);

  dim3 b256(256);
  int wblocks = (N / 16 + 3) / 4;   // one wave per 16 nodes, 4 waves/block
  int WW = C * C;
  int nscan = (N + 255) / 256;
  int degB = (E + 255) / 256;
  int castB = (3 * WW + 255) / 256;
  int fillB = (E + 255) / 256;
  int prepB = (N / 64) * (C / 64);
  int mB = 4 * B;
  int vsB = B;                       // vsum reduction blocks (one per graph)

  // ---- prep (5 launches) ----
  k_zero_region<<<dim3((2 * N + 255) / 256), b256, 0, stream>>>((unsigned int*)deg64, 2 * N);
  k_prep1<<<dim3(degB + prepB + castB), b256, 0, stream>>>(row, ew, deg64, rank, E, degB,
                                                           x, cur[0], curT, N, prepB,
                                                           Wq_w, Wk_w, Wo_w, W16, WW);
  k_scan1<<<dim3(nscan), b256, 0, stream>>>(deg64, dinv, bsum, N);
  k_scan3<<<dim3(nscan), b256, 0, stream>>>(deg64, bsum, row_ptr, N);
  k_prep2<<<dim3(fillB + 2 * wblocks), b256, 0, stream>>>(row, col, ew, rank, row_ptr, dinv,
                                                          edge_s, E, fillB,
                                                          cur[0], W16, Wq_b, Wk_b,
                                                          qs16, ksT, N, wblocks);

  // ---- 4 propagation iterations (2 launches each) ----
  for (int it = 0; it < 4; it++){
    int ksB = (it == 0) ? B : 0;     // ksum reduction rides along iteration 0
    k_M<<<dim3(mB + vsB + ksB), b256, 0, stream>>>(ksT, curT, MT, vsum, ksum,
                                                   N, PG, mB, vsB, ksB);
    k_phase2<<<dim3(wblocks), b256, 0, stream>>>(qs16, MT, vsum, ksum, n_nodes, denom,
                                                 row_ptr, edge_s,
                                                 (const unsigned int*)cur[it],
                                                 cur[it + 1], curT,
                                                 N, PG, (it == 0) ? 1 : 0);
  }

  k_final<<<dim3(wblocks), b256, 0, stream>>>(x, cur[1], cur[2], cur[3], cur[4],
                                              W16 + 2 * WW, Wo_b, out, N);
}

// Round 7
// 364.631 us; speedup vs baseline: 1.4737x; 1.4737x over previous
//
#include <hip/hip_runtime.h>
#include <stdint.h>

#define C 128

typedef __attribute__((ext_vector_type(8))) short bfrag;   // 8 x bf16 (4 VGPRs)
typedef __attribute__((ext_vector_type(4))) float ffrag;   // 4 x f32 accum

__device__ __forceinline__ unsigned short f2bf(float f){
  union { float f; unsigned int i; } v; v.f = f;
  unsigned int x = v.i;
  unsigned int r = x + 0x7fffu + ((x >> 16) & 1u);   // round-to-nearest-even
  return (unsigned short)(r >> 16);
}
__device__ __forceinline__ float bf2f(unsigned short u){
  union { unsigned int i; float f; } v; v.i = ((unsigned int)u) << 16; return v.f;
}

// ---------------- zero deg64 ----------------
__global__ void k_zero_region(unsigned int* base, int nwords){
  int i = blockIdx.x * 256 + threadIdx.x;
  if (i < nwords) base[i] = 0u;
}

// ---------------- prep1: {deg/cnt atomics | x->cur0/curT | weight casts} ----------------
// deg64: high 32 = count, low 32 = weight in 24-bit fixed point; atomic return = rank.
__global__ __launch_bounds__(256) void k_prep1(
    const int* __restrict__ row, const float* __restrict__ w,
    unsigned long long* deg64, int* __restrict__ rank, int E, int degB,
    const float* __restrict__ x, unsigned short* __restrict__ cur0,
    unsigned short* __restrict__ curT, int N, int prepB,
    const float* __restrict__ Wq, const float* __restrict__ Wk,
    const float* __restrict__ Wo, unsigned short* __restrict__ W16, int WW){
  __shared__ unsigned short tile[64][66];
  int bx = blockIdx.x;
  if (bx < degB){
    int e = bx * 256 + threadIdx.x;
    if (e < E){
      int r = row[e];
      unsigned int wf = (unsigned int)(w[e] * 16777216.0f + 0.5f);   // w * 2^24
      unsigned long long old =
          atomicAdd(&deg64[r], 0x100000000ULL | (unsigned long long)wf);
      rank[e] = (int)(old >> 32);
    }
    return;
  }
  bx -= degB;
  if (bx < prepB){
    int ntiles = N >> 6;
    int n0 = (bx % ntiles) * 64;
    int c0 = (bx / ntiles) * 64;
    int tx = threadIdx.x & 63, ty = threadIdx.x >> 6;
    for (int r = ty; r < 64; r += 4){
      float v = x[(size_t)(n0 + r) * C + c0 + tx];
      unsigned short u = f2bf(v);
      cur0[(size_t)(n0 + r) * C + c0 + tx] = u;
      tile[r][tx] = u;
    }
    __syncthreads();
    for (int r = ty; r < 64; r += 4)
      curT[(size_t)(c0 + r) * N + n0 + tx] = tile[tx][r];
    return;
  }
  bx -= prepB;
  int i = bx * 256 + threadIdx.x;
  if (i < 3 * WW){
    const float* src = (i < WW) ? Wq : ((i < 2 * WW) ? Wk : Wo);
    int off = (i < WW) ? 0 : ((i < 2 * WW) ? WW : 2 * WW);
    W16[i] = f2bf(src[i - off]);
  }
}

// ---- scan stage 1: per-block sums of cnt (decoded from deg64) + dinv decode ----
__global__ void k_scan1(const unsigned long long* __restrict__ deg64,
                        float* __restrict__ dinv, int* bsum, int N){
  __shared__ int s[256];
  int b = blockIdx.x, t = threadIdx.x;
  int i = b * 256 + t;
  int cnt = 0;
  if (i < N){
    unsigned long long v = deg64[i];
    cnt = (int)(v >> 32);
    unsigned int lo = (unsigned int)v;
    float d = (float)lo * (1.0f / 16777216.0f);
    dinv[i] = lo > 0u ? 1.0f / sqrtf(d) : 0.f;
  }
  s[t] = cnt;
  __syncthreads();
  for (int o = 128; o; o >>= 1){ if (t < o) s[t] += s[t + o]; __syncthreads(); }
  if (t == 0) bsum[b] = s[0];
}

// ---- scan stage 2: each block sums bsum[0..b) itself, then local inclusive scan ----
__global__ void k_scan3(const unsigned long long* __restrict__ deg64,
                        const int* __restrict__ bsum, int* row_ptr, int N){
  __shared__ int s[256];
  int b = blockIdx.x, t = threadIdx.x;
  int i = b * 256 + t;
  int v = (i < N) ? (int)(deg64[i] >> 32) : 0;
  s[t] = v;
  __syncthreads();
  for (int o = 1; o < 256; o <<= 1){
    int u = (t >= o) ? s[t - o] : 0;
    __syncthreads(); s[t] += u; __syncthreads();
  }
  int base = 0;
  for (int j = 0; j < b; j++) base += bsum[j];
  int excl = base + s[t] - v;
  if (i < N) row_ptr[i] = excl;
  if (i == N - 1) row_ptr[N] = excl + v;
}

// ---------------- prep2: {CSR fill | both projections [MFMA]} ----------------
__global__ __launch_bounds__(256) void k_prep2(
    const int* __restrict__ row, const int* __restrict__ col,
    const float* __restrict__ w, const int* __restrict__ rank,
    const int* __restrict__ row_ptr, const float* __restrict__ dinv,
    int2* __restrict__ edge_s, int E, int fillB,
    const unsigned short* __restrict__ x, const unsigned short* __restrict__ W16,
    const float* __restrict__ Wq_b, const float* __restrict__ Wk_b,
    unsigned short* __restrict__ qs, unsigned short* __restrict__ ksT,
    int N, int wblocks){
  int bx = blockIdx.x;
  if (bx < fillB){
    int e = bx * 256 + threadIdx.x;
    if (e < E){
      int r = row[e], c = col[e];
      int p = row_ptr[r] + rank[e];
      float cf = dinv[r] * dinv[c] * w[e];
      int2 ed; ed.x = c; ed.y = __float_as_int(cf);
      edge_s[p] = ed;
    }
    return;
  }
  bx -= fillB;
  int transposed = bx >= wblocks;
  int lb = transposed ? bx - wblocks : bx;
  const unsigned short* W = transposed ? (W16 + C * C) : W16;
  const float* Wb = transposed ? Wk_b : Wq_b;
  unsigned short* out = transposed ? ksT : qs;

  int wv = threadIdx.x >> 6, l = threadIdx.x & 63;
  int m0 = (lb * 4 + wv) * 16;
  if (m0 >= N) return;
  int quad = l >> 4, lcol = l & 15;
  ffrag acc[8] = {};
  const unsigned short* Abase = x + (size_t)(m0 + lcol) * C + quad * 8;
#pragma unroll
  for (int s = 0; s < 4; s++){
    bfrag a = *(const bfrag*)(Abase + s * 32);
#pragma unroll
    for (int nt = 0; nt < 8; nt++){
      bfrag bb = *(const bfrag*)(W + (size_t)(nt * 16 + lcol) * C + s * 32 + quad * 8);
      acc[nt] = __builtin_amdgcn_mfma_f32_16x16x32_bf16(a, bb, acc[nt], 0, 0, 0);
    }
  }
  float q[8][4];
  float ss[4] = {0.f, 0.f, 0.f, 0.f};
#pragma unroll
  for (int nt = 0; nt < 8; nt++){
    float bias = Wb[nt * 16 + lcol];
#pragma unroll
    for (int r = 0; r < 4; r++){ float v = acc[nt][r] + bias; q[nt][r] = v; ss[r] += v * v; }
  }
#pragma unroll
  for (int off = 1; off < 16; off <<= 1){
#pragma unroll
    for (int r = 0; r < 4; r++) ss[r] += __shfl_xor(ss[r], off, 64);
  }
  float inv[4];
#pragma unroll
  for (int r = 0; r < 4; r++) inv[r] = 1.0f / sqrtf(fmaxf(ss[r], 1e-30f));
  if (!transposed){
#pragma unroll
    for (int nt = 0; nt < 8; nt++)
#pragma unroll
      for (int r = 0; r < 4; r++)
        out[(size_t)(m0 + quad * 4 + r) * C + nt * 16 + lcol] = f2bf(q[nt][r] * inv[r]);
  } else {
#pragma unroll
    for (int nt = 0; nt < 8; nt++){
      ushort4 pk;
      pk.x = f2bf(q[nt][0] * inv[0]); pk.y = f2bf(q[nt][1] * inv[1]);
      pk.z = f2bf(q[nt][2] * inv[2]); pk.w = f2bf(q[nt][3] * inv[3]);
      *(ushort4*)(out + (size_t)(nt * 16 + lcol) * N + m0 + quad * 4) = pk;
    }
  }
}

// ---------------- merged per-iteration mid kernel ----------------
// blocks [0, mB):                 M[b] = Ks_b^T Cur_b  (MFMA)
// blocks [mB, mB+vsB):            vsum[b][d] = sum_n curT[d][b*PG+n]  (direct write)
// blocks [mB+vsB, mB+vsB+ksB):    ksum[b][d] = sum_n ksT[d][b*PG+n]   (it0 only)
// rest:                           GCN CSR gather (one node per wave, 8-edge MLP)
__global__ __launch_bounds__(256) void k_mid(const unsigned short* __restrict__ ksT,
      const unsigned short* __restrict__ curT, unsigned short* __restrict__ MT,
      const int* __restrict__ row_ptr, const int2* __restrict__ edge_s,
      const unsigned int* __restrict__ cur32, unsigned int* __restrict__ gcn32,
      float* __restrict__ vsum, float* __restrict__ ksum,
      int N, int PG, int mB, int vsB, int ksB, int gcnB){
  int bx = blockIdx.x;
  if (bx < mB){
    int wv = threadIdx.x >> 6, l = threadIdx.x & 63;
    int b = bx >> 2;
    int gw = (bx & 3) * 4 + wv;
    int itile = gw & 7, jh = gw >> 3;
    int quad = l >> 4, lcol = l & 15;
    ffrag acc[4] = {};
    const unsigned short* Arow = ksT + (size_t)(itile * 16 + lcol) * N + (size_t)b * PG + quad * 8;
    const unsigned short* B0 = curT + (size_t)b * PG + quad * 8;
    int steps = PG / 32;
    for (int s = 0; s < steps; s++){
      bfrag a = *(const bfrag*)(Arow + s * 32);
#pragma unroll
      for (int jt = 0; jt < 4; jt++){
        bfrag bb = *(const bfrag*)(B0 + (size_t)((jh * 4 + jt) * 16 + lcol) * N + s * 32);
        acc[jt] = __builtin_amdgcn_mfma_f32_16x16x32_bf16(a, bb, acc[jt], 0, 0, 0);
      }
    }
    unsigned short* MTb = MT + (size_t)b * C * C;
    int i0 = itile * 16 + quad * 4;
#pragma unroll
    for (int jt = 0; jt < 4; jt++){
      int j = (jh * 4 + jt) * 16 + lcol;
      ushort4 pk;
      pk.x = f2bf(acc[jt][0]); pk.y = f2bf(acc[jt][1]);
      pk.z = f2bf(acc[jt][2]); pk.w = f2bf(acc[jt][3]);
      *(ushort4*)(MTb + (size_t)j * C + i0) = pk;
    }
    return;
  }
  bx -= mB;
  if (bx < vsB + ksB){
    const unsigned short* src = (bx < vsB) ? curT : ksT;
    float* dst = (bx < vsB) ? vsum : ksum;
    int b = (bx < vsB) ? bx : (bx - vsB);
    int wv = threadIdx.x >> 6, l = threadIdx.x & 63;
    for (int d = wv * 32; d < wv * 32 + 32; d++){
      float s = 0.f;
      for (int n0 = l * 8; n0 < PG; n0 += 512){
        bfrag v = *(const bfrag*)(src + (size_t)d * N + (size_t)b * PG + n0);
#pragma unroll
        for (int j = 0; j < 8; j++) s += bf2f((unsigned short)v[j]);
      }
#pragma unroll
      for (int off = 32; off; off >>= 1) s += __shfl_xor(s, off, 64);
      if (l == 0) dst[b * C + d] = s;
    }
    return;
  }
  bx -= vsB + ksB;
  if (bx < gcnB){
    int nid = bx * 4 + (threadIdx.x >> 6);
    int c = threadIdx.x & 63;                 // channel-pair index
    if (nid >= N) return;
    int s = row_ptr[nid], e = row_ptr[nid + 1];
    float a0 = 0.f, a1 = 0.f;
    int p = s;
    for (; p + 8 <= e; p += 8){               // 8-wide: double memory-level parallelism
      int2 e0 = edge_s[p],     e1 = edge_s[p + 1];
      int2 e2 = edge_s[p + 2], e3 = edge_s[p + 3];
      int2 e4 = edge_s[p + 4], e5 = edge_s[p + 5];
      int2 e6 = edge_s[p + 6], e7 = edge_s[p + 7];
      unsigned int u0 = cur32[(size_t)e0.x * 64 + c];
      unsigned int u1 = cur32[(size_t)e1.x * 64 + c];
      unsigned int u2 = cur32[(size_t)e2.x * 64 + c];
      unsigned int u3 = cur32[(size_t)e3.x * 64 + c];
      unsigned int u4 = cur32[(size_t)e4.x * 64 + c];
      unsigned int u5 = cur32[(size_t)e5.x * 64 + c];
      unsigned int u6 = cur32[(size_t)e6.x * 64 + c];
      unsigned int u7 = cur32[(size_t)e7.x * 64 + c];
      float f0 = __int_as_float(e0.y), f1 = __int_as_float(e1.y);
      float f2 = __int_as_float(e2.y), f3 = __int_as_float(e3.y);
      float f4 = __int_as_float(e4.y), f5 = __int_as_float(e5.y);
      float f6 = __int_as_float(e6.y), f7 = __int_as_float(e7.y);
      a0 += f0 * bf2f((unsigned short)(u0 & 0xffffu));
      a1 += f0 * bf2f((unsigned short)(u0 >> 16));
      a0 += f1 * bf2f((unsigned short)(u1 & 0xffffu));
      a1 += f1 * bf2f((unsigned short)(u1 >> 16));
      a0 += f2 * bf2f((unsigned short)(u2 & 0xffffu));
      a1 += f2 * bf2f((unsigned short)(u2 >> 16));
      a0 += f3 * bf2f((unsigned short)(u3 & 0xffffu));
      a1 += f3 * bf2f((unsigned short)(u3 >> 16));
      a0 += f4 * bf2f((unsigned short)(u4 & 0xffffu));
      a1 += f4 * bf2f((unsigned short)(u4 >> 16));
      a0 += f5 * bf2f((unsigned short)(u5 & 0xffffu));
      a1 += f5 * bf2f((unsigned short)(u5 >> 16));
      a0 += f6 * bf2f((unsigned short)(u6 & 0xffffu));
      a1 += f6 * bf2f((unsigned short)(u6 >> 16));
      a0 += f7 * bf2f((unsigned short)(u7 & 0xffffu));
      a1 += f7 * bf2f((unsigned short)(u7 >> 16));
    }
    for (; p + 4 <= e; p += 4){
      int2 e0 = edge_s[p],     e1 = edge_s[p + 1];
      int2 e2 = edge_s[p + 2], e3 = edge_s[p + 3];
      float f0 = __int_as_float(e0.y), f1 = __int_as_float(e1.y);
      float f2 = __int_as_float(e2.y), f3 = __int_as_float(e3.y);
      unsigned int u0 = cur32[(size_t)e0.x * 64 + c];
      unsigned int u1 = cur32[(size_t)e1.x * 64 + c];
      unsigned int u2 = cur32[(size_t)e2.x * 64 + c];
      unsigned int u3 = cur32[(size_t)e3.x * 64 + c];
      a0 += f0 * bf2f((unsigned short)(u0 & 0xffffu));
      a1 += f0 * bf2f((unsigned short)(u0 >> 16));
      a0 += f1 * bf2f((unsigned short)(u1 & 0xffffu));
      a1 += f1 * bf2f((unsigned short)(u1 >> 16));
      a0 += f2 * bf2f((unsigned short)(u2 & 0xffffu));
      a1 += f2 * bf2f((unsigned short)(u2 >> 16));
      a0 += f3 * bf2f((unsigned short)(u3 & 0xffffu));
      a1 += f3 * bf2f((unsigned short)(u3 >> 16));
    }
    for (; p < e; p++){
      int2 ed = edge_s[p];
      float cf = __int_as_float(ed.y);
      unsigned int u = cur32[(size_t)ed.x * 64 + c];
      a0 += cf * bf2f((unsigned short)(u & 0xffffu));
      a1 += cf * bf2f((unsigned short)(u >> 16));
    }
    gcn32[(size_t)nid * 64 + c] = ((unsigned int)f2bf(a1) << 16) | (unsigned int)f2bf(a0);
  }
}

// ---------------- phase2 [MFMA]: cur_{it+1} = 0.5*(gcn + attn); it0 also computes denom ----------------
__global__ __launch_bounds__(256) void k_phase2(const unsigned short* __restrict__ qs,
      const unsigned short* __restrict__ MT, const float* __restrict__ vsum,
      const float* __restrict__ ksum, const int* __restrict__ n_nodes,
      float* __restrict__ denom, const unsigned short* __restrict__ gcn16,
      unsigned short* __restrict__ curO, unsigned short* __restrict__ curT,
      int N, int PG, int it0){
  int wv = threadIdx.x >> 6, l = threadIdx.x & 63;
  int m0 = (blockIdx.x * 4 + wv) * 16;
  if (m0 >= N) return;
  int b = m0 / PG;
  int quad = l >> 4, lcol = l & 15;
  ffrag acc[8] = {};
  const unsigned short* Abase = qs + (size_t)(m0 + lcol) * C + quad * 8;
  const unsigned short* MTb = MT + (size_t)b * C * C;
  const float* ksb = ksum + b * C;
  float dsum = 0.f;
#pragma unroll
  for (int s = 0; s < 4; s++){
    bfrag a = *(const bfrag*)(Abase + s * 32);
    if (it0){
#pragma unroll
      for (int j = 0; j < 8; j++)
        dsum += bf2f((unsigned short)a[j]) * ksb[quad * 8 + s * 32 + j];
    }
#pragma unroll
    for (int dt = 0; dt < 8; dt++){
      bfrag bb = *(const bfrag*)(MTb + (size_t)(dt * 16 + lcol) * C + s * 32 + quad * 8);
      acc[dt] = __builtin_amdgcn_mfma_f32_16x16x32_bf16(a, bb, acc[dt], 0, 0, 0);
    }
  }
  float dn[4];
  if (it0){
    // reduce over the 4 quads holding row (m0+lcol): lanes lcol, lcol+16, lcol+32, lcol+48
    dsum += __shfl_xor(dsum, 16, 64);
    dsum += __shfl_xor(dsum, 32, 64);
    float dfull = dsum + (float)n_nodes[b];
    if (quad == 0) denom[m0 + lcol] = dfull;          // persist for later iterations
#pragma unroll
    for (int r = 0; r < 4; r++) dn[r] = __shfl(dfull, quad * 4 + r, 64);
  } else {
#pragma unroll
    for (int r = 0; r < 4; r++) dn[r] = denom[m0 + quad * 4 + r];
  }
#pragma unroll
  for (int dt = 0; dt < 8; dt++){
    int d = dt * 16 + lcol;
    float vs = vsum[b * C + d];
    ushort4 pk;
#pragma unroll
    for (int r = 0; r < 4; r++){
      int m = m0 + quad * 4 + r;
      float attn = (acc[dt][r] + vs) / dn[r];
      float g = bf2f(gcn16[(size_t)m * C + d]);
      unsigned short nb = f2bf(0.5f * (g + attn));   // BETA = 0.5
      curO[(size_t)m * C + d] = nb;
      ((unsigned short*)&pk)[r] = nb;
    }
    *(ushort4*)(curT + (size_t)d * N + m0 + quad * 4) = pk;
  }
}

// ---------------- out = (x + c1+c2+c3+c4) @ Wo^T + Wo_b  (FP32 OUTPUT)  [MFMA] ----------------
__global__ __launch_bounds__(256) void k_final(const float* __restrict__ x,
      const unsigned short* __restrict__ c1, const unsigned short* __restrict__ c2,
      const unsigned short* __restrict__ c3, const unsigned short* __restrict__ c4,
      const unsigned short* __restrict__ Wo, const float* __restrict__ Wob,
      float* __restrict__ out, int N){
  int wv = threadIdx.x >> 6, l = threadIdx.x & 63;
  int m0 = (blockIdx.x * 4 + wv) * 16;
  if (m0 >= N) return;
  int quad = l >> 4, lcol = l & 15;
  ffrag acc[8] = {};
  size_t rowoff = (size_t)(m0 + lcol) * C + quad * 8;
#pragma unroll
  for (int s = 0; s < 4; s++){
    size_t base = rowoff + s * 32;
    float4 xa0 = *(const float4*)(x + base);
    float4 xa1 = *(const float4*)(x + base + 4);
    bfrag b1 = *(const bfrag*)(c1 + base);
    bfrag b2 = *(const bfrag*)(c2 + base);
    bfrag b3 = *(const bfrag*)(c3 + base);
    bfrag b4 = *(const bfrag*)(c4 + base);
    float xs[8] = {xa0.x, xa0.y, xa0.z, xa0.w, xa1.x, xa1.y, xa1.z, xa1.w};
    bfrag a;
#pragma unroll
    for (int j = 0; j < 8; j++){
      float v = (((xs[j] + bf2f((unsigned short)b1[j])) + bf2f((unsigned short)b2[j]))
                 + bf2f((unsigned short)b3[j])) + bf2f((unsigned short)b4[j]);
      a[j] = (short)f2bf(v);
    }
#pragma unroll
    for (int ot = 0; ot < 8; ot++){
      bfrag bb = *(const bfrag*)(Wo + (size_t)(ot * 16 + lcol) * C + s * 32 + quad * 8);
      acc[ot] = __builtin_amdgcn_mfma_f32_16x16x32_bf16(a, bb, acc[ot], 0, 0, 0);
    }
  }
#pragma unroll
  for (int ot = 0; ot < 8; ot++){
    float bias = Wob[ot * 16 + lcol];
#pragma unroll
    for (int r = 0; r < 4; r++){
      out[(size_t)(m0 + quad * 4 + r) * C + ot * 16 + lcol] = acc[ot][r] + bias;   // fp32 store
    }
  }
}

// ================= host =================

extern "C" void kernel_launch(void* const* d_in, const int* in_sizes, int n_in,
                              void* d_out, int out_size, void* d_ws, size_t ws_size,
                              hipStream_t stream){
  const float* x    = (const float*)d_in[0];
  const int*   eidx = (const int*)d_in[1];
  const float* ew   = (const float*)d_in[2];
  const int*   n_nodes = (const int*)d_in[3];
  const float* Wq_w = (const float*)d_in[4];
  const float* Wq_b = (const float*)d_in[5];
  const float* Wk_w = (const float*)d_in[6];
  const float* Wk_b = (const float*)d_in[7];
  const float* Wo_w = (const float*)d_in[8];
  const float* Wo_b = (const float*)d_in[9];
  float* out = (float*)d_out;                  // fp32 output

  int N = in_sizes[0] / C;
  int E = in_sizes[2];
  int B = in_sizes[3];
  int PG = N / B;
  int BC = B * C;
  const int* row = eidx;
  const int* col = eidx + E;

  char* p = (char*)d_ws;
  auto alloc = [&](size_t bytes) -> void* {
    void* r = (void*)p; p += (bytes + 255) & ~(size_t)255; return r;
  };
  unsigned short* cur[5];
  for (int i = 0; i < 5; i++) cur[i] = (unsigned short*)alloc((size_t)N * C * 2);
  unsigned short* curT  = (unsigned short*)alloc((size_t)N * C * 2);
  unsigned short* qs16  = (unsigned short*)alloc((size_t)N * C * 2);
  unsigned short* ksT   = (unsigned short*)alloc((size_t)N * C * 2);
  unsigned short* gcn16 = (unsigned short*)alloc((size_t)N * C * 2);
  unsigned short* MT    = (unsigned short*)alloc((size_t)B * C * C * 2);
  unsigned short* W16   = (unsigned short*)alloc((size_t)3 * C * C * 2);  // Wq|Wk|Wo
  unsigned long long* deg64 = (unsigned long long*)alloc((size_t)N * 8);
  float*          dinv  = (float*)alloc((size_t)N * 4);
  int*            row_ptr = (int*)alloc((size_t)(N + 1) * 4);
  int*            rank  = (int*)alloc((size_t)E * 4);
  int*            bsum  = (int*)alloc(1024);
  int2*           edge_s = (int2*)alloc((size_t)E * 8);
  float*          ksum  = (float*)alloc((size_t)BC * 4);
  float*          vsum  = (float*)alloc((size_t)BC * 4);
  float*          denom = (float*)alloc((size_t)N * 4);

  dim3 b256(256);
  int wblocks = (N / 16 + 3) / 4;   // one wave per 16 nodes, 4 waves/block
  int WW = C * C;
  int nscan = (N + 255) / 256;
  int degB = (E + 255) / 256;
  int castB = (3 * WW + 255) / 256;
  int fillB = (E + 255) / 256;
  int prepB = (N / 64) * (C / 64);
  int mB = 4 * B;
  int gcnB = (N + 3) / 4;
  int vsB = B;                       // vsum reduction blocks (one per graph)

  // ---- prep (5 launches) ----
  k_zero_region<<<dim3((2 * N + 255) / 256), b256, 0, stream>>>((unsigned int*)deg64, 2 * N);
  k_prep1<<<dim3(degB + prepB + castB), b256, 0, stream>>>(row, ew, deg64, rank, E, degB,
                                                           x, cur[0], curT, N, prepB,
                                                           Wq_w, Wk_w, Wo_w, W16, WW);
  k_scan1<<<dim3(nscan), b256, 0, stream>>>(deg64, dinv, bsum, N);
  k_scan3<<<dim3(nscan), b256, 0, stream>>>(deg64, bsum, row_ptr, N);
  k_prep2<<<dim3(fillB + 2 * wblocks), b256, 0, stream>>>(row, col, ew, rank, row_ptr, dinv,
                                                          edge_s, E, fillB,
                                                          cur[0], W16, Wq_b, Wk_b,
                                                          qs16, ksT, N, wblocks);

  // ---- 4 propagation iterations (2 launches each) ----
  for (int it = 0; it < 4; it++){
    int ksB = (it == 0) ? B : 0;     // ksum reduction rides along iteration 0
    k_mid<<<dim3(mB + vsB + ksB + gcnB), b256, 0, stream>>>(ksT, curT, MT, row_ptr, edge_s,
                                                      (const unsigned int*)cur[it],
                                                      (unsigned int*)gcn16,
                                                      vsum, ksum,
                                                      N, PG, mB, vsB, ksB, gcnB);
    k_phase2<<<dim3(wblocks), b256, 0, stream>>>(qs16, MT, vsum, ksum, n_nodes, denom,
                                                 gcn16, cur[it + 1], curT,
                                                 N, PG, (it == 0) ? 1 : 0);
  }

  k_final<<<dim3(wblocks), b256, 0, stream>>>(x, cur[1], cur[2], cur[3], cur[4],
                                              W16 + 2 * WW, Wo_b, out, N);
}